// Round 4
// baseline (335.723 us; speedup 1.0000x reference)
//
#include <hip/hip_runtime.h>
#include <math.h>

#define B_SZ    16384
#define NNZ_PER 32
#define NNZ     (B_SZ * NNZ_PER)
#define FT_OUT  512
#define F_BIG   49152
#define F_SMALL 768
#define MODV    640

// prep_big grid
#define TP_A     1536              // W_ft tiles: 768 c-tiles(64) x 2 o-tiles(256)
// prep_small grid partition
#define TP_B     80                // W_fft 64x64 tiles: 8 ot x 10 ct
#define HISTB    (2 * MODV)        // 1280: one block per (side, histogram row r)
#define PREPS_GRID (TP_B + HISTB)

// main slicing: 16 slices x 32 features, slice-major Wt layout [s][col][32]
#define NSLICE  16
#define SL_F    32
#define MAIN_GRID (NSLICE * (B_SZ / 4))   // 65536 blocks, 4 rows each

// ---------------------------------------------------------------------------
// ws layout:
//   Wt_bf   : F_BIG*FT_OUT ushort      48 MB  slice-major bf16 weight
//   Wfft_t  : MODV*FT_OUT float        1.3 MB transposed small weight (fp32)
//   H       : 2*MODV*MODV float        3.3 MB weighted histograms
//   fft_acc : 2*MODV*FT_OUT float      2.6 MB H @ Wfft^T per side
//   partial : NSLICE*B_SZ float        1.0 MB per-slice partial dots
// ---------------------------------------------------------------------------

__device__ __forceinline__ unsigned short f32_to_bf16_rne(float f) {
    union { float f; unsigned int u; } v; v.f = f;
    unsigned int u = v.u;
    return (unsigned short)((u + 0x7fffu + ((u >> 16) & 1u)) >> 16);
}

__device__ __forceinline__ void unpack_bf16x2(unsigned int u, float& lo, float& hi) {
    union { unsigned int i; float f; } a, b;
    a.i = u << 16;            // even element
    b.i = u & 0xffff0000u;    // odd element
    lo = a.f; hi = b.f;
}

__device__ __forceinline__ float clip01(float x) {
    return fminf(fmaxf(x, 0.0f), 1.0f);
}

// ---- W_ft transpose+quantize into slice-major layout ----------------------
// dst[s][col][f] with s = o/32, f = o%32: main's slice s is a contiguous 3 MB
// region -> fits one XCD's 4 MB L2 with full cache-line utilization.
__global__ __launch_bounds__(256)
void prep_big(const float* __restrict__ W_ft, unsigned short* __restrict__ Wt) {
    __shared__ __align__(16) unsigned short tA[256][68];   // 34.8 KB
    int b = blockIdx.x;
    int tid = threadIdx.x;
    int ct = b >> 1, ot = b & 1;
    int c0 = ct * 64, o0 = ot * 256;
    int orow = tid >> 4, c4 = (tid & 15) * 4;
#pragma unroll
    for (int it = 0; it < 16; it++) {
        int oo = orow + it * 16;
        float4 f = *(const float4*)(W_ft + (size_t)(o0 + oo) * F_BIG + c0 + c4);
        tA[oo][c4 + 0] = f32_to_bf16_rne(f.x);
        tA[oo][c4 + 1] = f32_to_bf16_rne(f.y);
        tA[oo][c4 + 2] = f32_to_bf16_rne(f.z);
        tA[oo][c4 + 3] = f32_to_bf16_rne(f.w);
    }
    __syncthreads();
    // lane cc owns column c0+cc; och selects 64-o chunk; k walks 8-o groups.
    // global o = o0 + och*64 + k*8 + j  ->  slice s = o/32, in-slice f = o%32
    int cc = tid & 63, och = tid >> 6;      // och 0..3
    int obase = och * 64;
#pragma unroll
    for (int k = 0; k < 8; k++) {
        int o8 = obase + k * 8;
        uint4 pk;
        pk.x = (unsigned int)tA[o8 + 0][cc] | ((unsigned int)tA[o8 + 1][cc] << 16);
        pk.y = (unsigned int)tA[o8 + 2][cc] | ((unsigned int)tA[o8 + 3][cc] << 16);
        pk.z = (unsigned int)tA[o8 + 4][cc] | ((unsigned int)tA[o8 + 5][cc] << 16);
        pk.w = (unsigned int)tA[o8 + 6][cc] | ((unsigned int)tA[o8 + 7][cc] << 16);
        int og = o0 + o8;                    // global o of first elem (mult of 8)
        int s  = og >> 5;                    // slice
        int f  = og & 31;                    // offset within slice (0,8,16,24)
        *(uint4*)(Wt + ((size_t)s * F_BIG + (c0 + cc)) * SL_F + f) = pk;
    }
}

// ---- W_fft transpose + LDS-private histogram ------------------------------
__global__ __launch_bounds__(256)
void prep_small(const float* __restrict__ W_fft,
                const int* __restrict__ stm, const int* __restrict__ nstm,
                const float* __restrict__ vals,
                float* __restrict__ Wfft_t, float* __restrict__ H) {
    __shared__ __align__(16) float smem[64 * 65];          // 16.6 KB
    int b = blockIdx.x;
    int tid = threadIdx.x;
    if (b < TP_B) {
        float (*tB)[65] = (float (*)[65])smem;
        int nct = MODV / 64;
        int ot = b / nct, ct = b % nct;
        int c0 = ct * 64, o0 = ot * 64;
        int rr = tid >> 4, c4 = (tid & 15) * 4;
#pragma unroll
        for (int it = 0; it < 4; it++) {
            int oo = rr + it * 16;
            float4 f = *(const float4*)(W_fft + (size_t)(o0 + oo) * F_SMALL + c0 + c4);
            tB[oo][c4 + 0] = f.x; tB[oo][c4 + 1] = f.y;
            tB[oo][c4 + 2] = f.z; tB[oo][c4 + 3] = f.w;
        }
        __syncthreads();
#pragma unroll
        for (int it = 0; it < 4; it++) {
            int idx = tid + it * 256;
            int cc = idx >> 4, g = idx & 15;
            float4 v = make_float4(tB[g * 4 + 0][cc], tB[g * 4 + 1][cc],
                                   tB[g * 4 + 2][cc], tB[g * 4 + 3][cc]);
            *(float4*)(Wfft_t + (size_t)(c0 + cc) * FT_OUT + o0 + g * 4) = v;
        }
    } else {
        // one block per (side, r): build 640-float histogram row in LDS.
        // COO rows are repeat(arange(B),32) so r = (j/32) % 640 is index-known.
        float* hrow = smem;
        int hb   = b - TP_B;                         // 0..1279
        int side = (hb >= MODV) ? 1 : 0;
        int r    = hb - side * MODV;
        const int* cols = (side ? nstm : stm) + NNZ; // col indices at offset NNZ
        for (int i = tid; i < MODV; i += 256) hrow[i] = 0.0f;
        __syncthreads();
        int nb  = (B_SZ - r + MODV - 1) / MODV;      // batch rows with row%640==r
        int tot = nb * NNZ_PER;
        for (int idx = tid; idx < tot; idx += 256) {
            int j = r * NNZ_PER + (idx >> 5) * (MODV * NNZ_PER) + (idx & 31);
            int c = cols[j] % MODV;
            atomicAdd(&hrow[c], vals[j]);
        }
        __syncthreads();
        float* dst = H + ((size_t)side * MODV + r) * MODV;
        for (int i = tid; i < MODV; i += 256) dst[i] = hrow[i];
    }
}

// acc[side][s][o] = sum_cc H[side][s][cc] * Wfft_t[cc][o]
// 320 blocks (TLP for latency hiding) + transposed LDS (ds_read_b128 per cc)
// + 8-deep register prefetch of the Wfft_t column.
__global__ __launch_bounds__(512)
void fft_gemm(const float* __restrict__ H, const float* __restrict__ Wfft_t,
              float* __restrict__ acc) {
    __shared__ float hst[MODV][4];                   // [cc][j], 10 KB
    int o = threadIdx.x;                             // 0..511
    int b = blockIdx.x;
    int side = b / 160;
    int s0   = (b % 160) * 4;
    const float* Hs = H + ((size_t)side * MODV + s0) * MODV;
    for (int t = threadIdx.x; t < 4 * MODV; t += 512) {
        int j = t / MODV, cc = t - j * MODV;
        hst[cc][j] = Hs[t];
    }
    __syncthreads();
    float a0 = 0, a1 = 0, a2 = 0, a3 = 0;
    const float* wp = Wfft_t + o;
    for (int cc0 = 0; cc0 < MODV; cc0 += 8) {
        float w[8];
#pragma unroll
        for (int u = 0; u < 8; u++) w[u] = wp[(size_t)(cc0 + u) * FT_OUT];
#pragma unroll
        for (int u = 0; u < 8; u++) {
            float4 hv = *(const float4*)hst[cc0 + u];
            a0 += hv.x * w[u]; a1 += hv.y * w[u];
            a2 += hv.z * w[u]; a3 += hv.w * w[u];
        }
    }
    float* dst = acc + ((size_t)side * MODV + s0) * FT_OUT + o;
    dst[0] = a0; dst[FT_OUT] = a1;
    dst[2 * FT_OUT] = a2; dst[3 * FT_OUT] = a3;
}

// XCD-sliced gather main, issue-optimized (R4).
// slice = bid%8 (+8 in phase 1): all blocks on XCD x gather only from slice
// x's contiguous 3 MB -> L2-resident. R3 proved the traffic model (FETCH
// 486->76 MB) but was issue-bound at ~480 instr/wave. R4 mapping:
//   q  = lane>>3 : k-eighth   (k = kb*8+q, kb=0..3)
//   fp = lane&7  : feature quad (features fp*4..fp*4+3 of the slice)
// -> uint2 gathers (4 bf16/load, 8 loads/wave, all in flight together),
//    cols+vals staged TRANSPOSED in LDS so each lane reads its 4 cols as one
//    ds_read_b128, 32-bit offset math, 3-step shfl_xor butterfly.
__global__ __launch_bounds__(256)
void main_slice(const int* __restrict__ stm, const int* __restrict__ nstm,
                const float* __restrict__ vals,
                const unsigned short* __restrict__ Wt,
                const float* __restrict__ b_ft, const float* __restrict__ b_fft,
                const float* __restrict__ fft_acc,
                const float* __restrict__ W_out, float* __restrict__ partial) {
    int bid   = blockIdx.x;
    int phase = bid >> 15;                       // 32768 blocks per phase
    int slice = (bid & 7) + (phase << 3);
    int rowgrp = (bid & 32767) >> 3;
    int row0 = rowgrp * 4;
    int tid = threadIdx.x;

    __shared__ int   s_ct[4][2][32];   // [row][side][q*4+kb] transposed cols
    __shared__ float s_vf[4][32];      // [row][q*4+kb] transposed vals

    {
        int r = tid >> 6, rem = tid & 63;
        int side = rem >> 5, k = rem & 31;
        int tk = (k & 7) * 4 + (k >> 3);         // transpose: [q][kb]
        const int* arr = side ? nstm : stm;
        s_ct[r][side][tk] = arr[NNZ + (row0 + r) * NNZ_PER + k];
        if (side == 0)
            s_vf[r][tk] = vals[(row0 + r) * NNZ_PER + k];
    }
    __syncthreads();

    int wid  = tid >> 6;
    int lane = tid & 63;
    int row  = row0 + wid;
    int q    = lane >> 3;
    int fp   = lane & 7;

    // base: slice block (64 B/col) + this lane's feature-quad byte offset
    const char* wsb = (const char*)Wt + (size_t)slice * F_BIG * 64 + fp * 8;

    uint4  c0 = *(const uint4*)&s_ct[wid][0][q * 4];
    uint4  c1 = *(const uint4*)&s_ct[wid][1][q * 4];
    float4 vf = *(const float4*)&s_vf[wid][q * 4];

    // issue all 8 gathers back-to-back (ILP; latency overlapped)
    uint2 w00 = *(const uint2*)(wsb + ((size_t)c0.x << 6));
    uint2 w01 = *(const uint2*)(wsb + ((size_t)c0.y << 6));
    uint2 w02 = *(const uint2*)(wsb + ((size_t)c0.z << 6));
    uint2 w03 = *(const uint2*)(wsb + ((size_t)c0.w << 6));
    uint2 w10 = *(const uint2*)(wsb + ((size_t)c1.x << 6));
    uint2 w11 = *(const uint2*)(wsb + ((size_t)c1.y << 6));
    uint2 w12 = *(const uint2*)(wsb + ((size_t)c1.z << 6));
    uint2 w13 = *(const uint2*)(wsb + ((size_t)c1.w << 6));

    float a[4] = {0, 0, 0, 0}, g[4] = {0, 0, 0, 0};
    float lo, hi;
    unpack_bf16x2(w00.x, lo, hi); a[0] += vf.x * lo; a[1] += vf.x * hi;
    unpack_bf16x2(w00.y, lo, hi); a[2] += vf.x * lo; a[3] += vf.x * hi;
    unpack_bf16x2(w01.x, lo, hi); a[0] += vf.y * lo; a[1] += vf.y * hi;
    unpack_bf16x2(w01.y, lo, hi); a[2] += vf.y * lo; a[3] += vf.y * hi;
    unpack_bf16x2(w02.x, lo, hi); a[0] += vf.z * lo; a[1] += vf.z * hi;
    unpack_bf16x2(w02.y, lo, hi); a[2] += vf.z * lo; a[3] += vf.z * hi;
    unpack_bf16x2(w03.x, lo, hi); a[0] += vf.w * lo; a[1] += vf.w * hi;
    unpack_bf16x2(w03.y, lo, hi); a[2] += vf.w * lo; a[3] += vf.w * hi;
    unpack_bf16x2(w10.x, lo, hi); g[0] += vf.x * lo; g[1] += vf.x * hi;
    unpack_bf16x2(w10.y, lo, hi); g[2] += vf.x * lo; g[3] += vf.x * hi;
    unpack_bf16x2(w11.x, lo, hi); g[0] += vf.y * lo; g[1] += vf.y * hi;
    unpack_bf16x2(w11.y, lo, hi); g[2] += vf.y * lo; g[3] += vf.y * hi;
    unpack_bf16x2(w12.x, lo, hi); g[0] += vf.z * lo; g[1] += vf.z * hi;
    unpack_bf16x2(w12.y, lo, hi); g[2] += vf.z * lo; g[3] += vf.z * hi;
    unpack_bf16x2(w13.x, lo, hi); g[0] += vf.w * lo; g[1] += vf.w * hi;
    unpack_bf16x2(w13.y, lo, hi); g[2] += vf.w * lo; g[3] += vf.w * hi;

    // butterfly across the 8 k-eighths (lane bits 3,4,5)
#pragma unroll
    for (int i = 0; i < 4; i++) {
        a[i] += __shfl_xor(a[i], 8, 64);
        a[i] += __shfl_xor(a[i], 16, 64);
        a[i] += __shfl_xor(a[i], 32, 64);
        g[i] += __shfl_xor(g[i], 8, 64);
        g[i] += __shfl_xor(g[i], 16, 64);
        g[i] += __shfl_xor(g[i], 32, 64);
    }

    int fo = slice * SL_F + fp * 4;              // original feature index
    float bf[4], bb[4], wo0[4], wo1[4], fa0[4], fa1[4];
    *(float4*)bf  = *(const float4*)(b_ft + fo);
    *(float4*)bb  = *(const float4*)(b_fft + fo);
    *(float4*)wo0 = *(const float4*)(W_out + fo);
    *(float4*)wo1 = *(const float4*)(W_out + FT_OUT + fo);
#pragma unroll
    for (int i = 0; i < 4; i++) { fa0[i] = 0.0f; fa1[i] = 0.0f; }
    if (row < MODV) {
        *(float4*)fa0 = *(const float4*)(fft_acc + (size_t)row * FT_OUT + fo);
        *(float4*)fa1 = *(const float4*)(fft_acc + (size_t)(MODV + row) * FT_OUT + fo);
    }

    float dot = 0.0f;
#pragma unroll
    for (int i = 0; i < 4; i++) {
        dot += clip01(a[i] + bf[i] + bb[i] + fa0[i]) * wo0[i];
        dot += clip01(g[i] + bf[i] + bb[i] + fa1[i]) * wo1[i];
    }

    // each feature is held by 8 lanes (the q-group) -> wave sum = 8x truth
#pragma unroll
    for (int off = 32; off > 0; off >>= 1)
        dot += __shfl_down(dot, off, 64);
    if (lane == 0)
        partial[(size_t)slice * B_SZ + row] = dot * 0.125f;
}

__global__ __launch_bounds__(256)
void finish(const float* __restrict__ partial, const float* __restrict__ b_out,
            float* __restrict__ out) {
    int row = blockIdx.x * 256 + threadIdx.x;
    float s = b_out[0];
#pragma unroll
    for (int j = 0; j < NSLICE; j++)
        s += partial[(size_t)j * B_SZ + row];
    out[row] = 1.0f / (1.0f + expf(-s));
}

extern "C" void kernel_launch(void* const* d_in, const int* in_sizes, int n_in,
                              void* d_out, int out_size, void* d_ws, size_t ws_size,
                              hipStream_t stream) {
    const int*   stm   = (const int*)d_in[0];
    const int*   nstm  = (const int*)d_in[1];
    const float* vals  = (const float*)d_in[2];
    // d_in[3]: size scalar (compile-time B_SZ)
    const float* W_ft  = (const float*)d_in[4];
    const float* b_ft  = (const float*)d_in[5];
    const float* W_fft = (const float*)d_in[6];
    const float* b_fft = (const float*)d_in[7];
    const float* W_out = (const float*)d_in[8];
    const float* b_out = (const float*)d_in[9];
    float* out = (float*)d_out;

    unsigned short* Wt_bf = (unsigned short*)d_ws;                  // F_BIG*FT_OUT ushort
    float* Wfft_t  = (float*)(Wt_bf + (size_t)F_BIG * FT_OUT);      // MODV*FT_OUT
    float* H       = Wfft_t + (size_t)MODV * FT_OUT;                // 2*MODV*MODV
    float* fft_acc = H + (size_t)2 * MODV * MODV;                   // 2*MODV*FT_OUT
    float* partial = fft_acc + (size_t)2 * MODV * FT_OUT;           // NSLICE*B_SZ

    prep_small<<<PREPS_GRID, 256, 0, stream>>>(W_fft, stm, nstm, vals, Wfft_t, H);
    fft_gemm<<<320, 512, 0, stream>>>(H, Wfft_t, fft_acc);
    prep_big<<<TP_A, 256, 0, stream>>>(W_ft, Wt_bf);
    main_slice<<<MAIN_GRID, 256, 0, stream>>>(stm, nstm, vals, Wt_bf, b_ft, b_fft,
                                              fft_acc, W_out, partial);
    finish<<<B_SZ / 256, 256, 0, stream>>>(partial, b_out, out);
}

// Round 5
// 332.620 us; speedup vs baseline: 1.0093x; 1.0093x over previous
//
#include <hip/hip_runtime.h>
#include <math.h>

#define B_SZ    16384
#define NNZ_PER 32
#define NNZ     (B_SZ * NNZ_PER)
#define FT_OUT  512
#define F_BIG   49152
#define F_SMALL 768
#define MODV    640

// prep_big grid
#define TP_A     1536              // W_ft tiles: 768 c-tiles(64) x 2 o-tiles(256)
// prep_small grid partition
#define TP_B     80                // W_fft 64x64 tiles: 8 ot x 10 ct
#define HISTB    (2 * MODV)        // 1280: one block per (side, histogram row r)
#define PREPS_GRID (TP_B + HISTB)

// main slicing: 16 slices x 32 features, slice-major Wt layout [s][col][32]
#define NSLICE  16
#define SL_F    32
#define MAIN_GRID (NSLICE * (B_SZ / 4))   // 65536 blocks, 4 rows each

// ---------------------------------------------------------------------------
// ws layout:
//   Wt_bf   : F_BIG*FT_OUT ushort      48 MB  slice-major bf16 weight
//   Wfft_t  : MODV*FT_OUT float        1.3 MB transposed small weight (fp32)
//   H       : 2*MODV*MODV float        3.3 MB weighted histograms
//   fft_acc : 2*MODV*FT_OUT float      2.6 MB H @ Wfft^T per side
//   partial : NSLICE*B_SZ float        1.0 MB per-slice partial dots
// ---------------------------------------------------------------------------

__device__ __forceinline__ unsigned short f32_to_bf16_rne(float f) {
    union { float f; unsigned int u; } v; v.f = f;
    unsigned int u = v.u;
    return (unsigned short)((u + 0x7fffu + ((u >> 16) & 1u)) >> 16);
}

__device__ __forceinline__ void unpack_bf16x2(unsigned int u, float& lo, float& hi) {
    union { unsigned int i; float f; } a, b;
    a.i = u << 16;            // even element
    b.i = u & 0xffff0000u;    // odd element
    lo = a.f; hi = b.f;
}

__device__ __forceinline__ float clip01(float x) {
    return fminf(fmaxf(x, 0.0f), 1.0f);
}

// ---- W_ft transpose+quantize into slice-major layout ----------------------
// dst[s][col][f] with s = o/32, f = o%32: main's slice s is a contiguous 3 MB
// region -> fits one XCD's 4 MB L2 with full cache-line utilization.
__global__ __launch_bounds__(256)
void prep_big(const float* __restrict__ W_ft, unsigned short* __restrict__ Wt) {
    __shared__ __align__(16) unsigned short tA[256][68];   // 34.8 KB
    int b = blockIdx.x;
    int tid = threadIdx.x;
    int ct = b >> 1, ot = b & 1;
    int c0 = ct * 64, o0 = ot * 256;
    int orow = tid >> 4, c4 = (tid & 15) * 4;
#pragma unroll
    for (int it = 0; it < 16; it++) {
        int oo = orow + it * 16;
        float4 f = *(const float4*)(W_ft + (size_t)(o0 + oo) * F_BIG + c0 + c4);
        tA[oo][c4 + 0] = f32_to_bf16_rne(f.x);
        tA[oo][c4 + 1] = f32_to_bf16_rne(f.y);
        tA[oo][c4 + 2] = f32_to_bf16_rne(f.z);
        tA[oo][c4 + 3] = f32_to_bf16_rne(f.w);
    }
    __syncthreads();
    // lane cc owns column c0+cc; och selects 64-o chunk; k walks 8-o groups.
    // global o = o0 + och*64 + k*8 + j  ->  slice s = o/32, in-slice f = o%32
    int cc = tid & 63, och = tid >> 6;      // och 0..3
    int obase = och * 64;
#pragma unroll
    for (int k = 0; k < 8; k++) {
        int o8 = obase + k * 8;
        uint4 pk;
        pk.x = (unsigned int)tA[o8 + 0][cc] | ((unsigned int)tA[o8 + 1][cc] << 16);
        pk.y = (unsigned int)tA[o8 + 2][cc] | ((unsigned int)tA[o8 + 3][cc] << 16);
        pk.z = (unsigned int)tA[o8 + 4][cc] | ((unsigned int)tA[o8 + 5][cc] << 16);
        pk.w = (unsigned int)tA[o8 + 6][cc] | ((unsigned int)tA[o8 + 7][cc] << 16);
        int og = o0 + o8;                    // global o of first elem (mult of 8)
        int s  = og >> 5;                    // slice
        int f  = og & 31;                    // offset within slice (0,8,16,24)
        *(uint4*)(Wt + ((size_t)s * F_BIG + (c0 + cc)) * SL_F + f) = pk;
    }
}

// ---- W_fft transpose + LDS-private histogram ------------------------------
__global__ __launch_bounds__(256)
void prep_small(const float* __restrict__ W_fft,
                const int* __restrict__ stm, const int* __restrict__ nstm,
                const float* __restrict__ vals,
                float* __restrict__ Wfft_t, float* __restrict__ H) {
    __shared__ __align__(16) float smem[64 * 65];          // 16.6 KB
    int b = blockIdx.x;
    int tid = threadIdx.x;
    if (b < TP_B) {
        float (*tB)[65] = (float (*)[65])smem;
        int nct = MODV / 64;
        int ot = b / nct, ct = b % nct;
        int c0 = ct * 64, o0 = ot * 64;
        int rr = tid >> 4, c4 = (tid & 15) * 4;
#pragma unroll
        for (int it = 0; it < 4; it++) {
            int oo = rr + it * 16;
            float4 f = *(const float4*)(W_fft + (size_t)(o0 + oo) * F_SMALL + c0 + c4);
            tB[oo][c4 + 0] = f.x; tB[oo][c4 + 1] = f.y;
            tB[oo][c4 + 2] = f.z; tB[oo][c4 + 3] = f.w;
        }
        __syncthreads();
#pragma unroll
        for (int it = 0; it < 4; it++) {
            int idx = tid + it * 256;
            int cc = idx >> 4, g = idx & 15;
            float4 v = make_float4(tB[g * 4 + 0][cc], tB[g * 4 + 1][cc],
                                   tB[g * 4 + 2][cc], tB[g * 4 + 3][cc]);
            *(float4*)(Wfft_t + (size_t)(c0 + cc) * FT_OUT + o0 + g * 4) = v;
        }
    } else {
        // one block per (side, r): build 640-float histogram row in LDS.
        // COO rows are repeat(arange(B),32) so r = (j/32) % 640 is index-known.
        float* hrow = smem;
        int hb   = b - TP_B;                         // 0..1279
        int side = (hb >= MODV) ? 1 : 0;
        int r    = hb - side * MODV;
        const int* cols = (side ? nstm : stm) + NNZ; // col indices at offset NNZ
        for (int i = tid; i < MODV; i += 256) hrow[i] = 0.0f;
        __syncthreads();
        int nb  = (B_SZ - r + MODV - 1) / MODV;      // batch rows with row%640==r
        int tot = nb * NNZ_PER;
        for (int idx = tid; idx < tot; idx += 256) {
            int j = r * NNZ_PER + (idx >> 5) * (MODV * NNZ_PER) + (idx & 31);
            int c = cols[j] % MODV;
            atomicAdd(&hrow[c], vals[j]);
        }
        __syncthreads();
        float* dst = H + ((size_t)side * MODV + r) * MODV;
        for (int i = tid; i < MODV; i += 256) dst[i] = hrow[i];
    }
}

// acc[side][s][o] = sum_cc H[side][s][cc] * Wfft_t[cc][o]
// 320 blocks (TLP for latency hiding) + transposed LDS (ds_read_b128 per cc)
// + 8-deep register prefetch of the Wfft_t column.
__global__ __launch_bounds__(512)
void fft_gemm(const float* __restrict__ H, const float* __restrict__ Wfft_t,
              float* __restrict__ acc) {
    __shared__ float hst[MODV][4];                   // [cc][j], 10 KB
    int o = threadIdx.x;                             // 0..511
    int b = blockIdx.x;
    int side = b / 160;
    int s0   = (b % 160) * 4;
    const float* Hs = H + ((size_t)side * MODV + s0) * MODV;
    for (int t = threadIdx.x; t < 4 * MODV; t += 512) {
        int j = t / MODV, cc = t - j * MODV;
        hst[cc][j] = Hs[t];
    }
    __syncthreads();
    float a0 = 0, a1 = 0, a2 = 0, a3 = 0;
    const float* wp = Wfft_t + o;
    for (int cc0 = 0; cc0 < MODV; cc0 += 8) {
        float w[8];
#pragma unroll
        for (int u = 0; u < 8; u++) w[u] = wp[(size_t)(cc0 + u) * FT_OUT];
#pragma unroll
        for (int u = 0; u < 8; u++) {
            float4 hv = *(const float4*)hst[cc0 + u];
            a0 += hv.x * w[u]; a1 += hv.y * w[u];
            a2 += hv.z * w[u]; a3 += hv.w * w[u];
        }
    }
    float* dst = acc + ((size_t)side * MODV + s0) * FT_OUT + o;
    dst[0] = a0; dst[FT_OUT] = a1;
    dst[2 * FT_OUT] = a2; dst[3 * FT_OUT] = a3;
}

// XCD-sliced gather main, R5: 32-bit saddr addressing + halving butterfly.
// slice = bid%8 (+8 in phase 1): L2-resident gather (proven R3: FETCH 486->76MB).
// Lane mapping: q = lane>>3 (k-eighth, k = q*4+kb), fp = lane&7 (feature quad).
// R5 changes vs R4 (which matched R3's VALU cycles but halved MLP and tripled
// shfl -> slower):
//  - staging stores col<<6 (byte offsets); loads become
//    v_add_u32 + global_load_dwordx2 v,voff,s[slice_base] (no 64-bit math)
//  - k-merge: halving butterfly (keep half, ship half) -> 7 shfl instead of 24;
//    lane ends owning ONE (side,feat) channel: side=b5, f=fp*4+2*b3+b4
//  - scalar per-lane epilogue (4 dword loads) instead of 6x float4 per lane
__global__ __launch_bounds__(256)
void main_slice(const int* __restrict__ stm, const int* __restrict__ nstm,
                const float* __restrict__ vals,
                const unsigned short* __restrict__ Wt,
                const float* __restrict__ b_ft, const float* __restrict__ b_fft,
                const float* __restrict__ fft_acc,
                const float* __restrict__ W_out, float* __restrict__ partial) {
    int bid   = blockIdx.x;
    int phase = bid >> 15;                       // 32768 blocks per phase
    int slice = (bid & 7) + (phase << 3);
    int rowgrp = (bid & 32767) >> 3;
    int row0 = rowgrp * 4;
    int tid = threadIdx.x;

    __shared__ __align__(16) unsigned s_ct[4][2][32];  // [row][side][q*4+kb] col<<6
    __shared__ __align__(16) float    s_vf[4][32];     // [row][q*4+kb] vals

    {
        int r = tid >> 6, rem = tid & 63;
        int side = rem >> 5, k = rem & 31;
        int tk = (k & 7) * 4 + (k >> 3);         // transpose: [q][kb]
        const int* arr = side ? nstm : stm;
        s_ct[r][side][tk] = (unsigned)arr[NNZ + (row0 + r) * NNZ_PER + k] << 6;
        if (side == 0)
            s_vf[r][tk] = vals[(row0 + r) * NNZ_PER + k];
    }
    __syncthreads();

    int wid  = tid >> 6;
    int lane = tid & 63;
    int row  = row0 + wid;
    int q    = lane >> 3;
    int fp   = lane & 7;

    // wave-uniform slice base (SGPR pair); per-lane 32-bit byte offsets
    const char* base = (const char*)Wt + (size_t)slice * ((size_t)F_BIG * 64);
    unsigned fb = (unsigned)fp * 8u;

    uint4  c0 = *(const uint4*)&s_ct[wid][0][q * 4];
    uint4  c1 = *(const uint4*)&s_ct[wid][1][q * 4];
    float4 vf = *(const float4*)&s_vf[wid][q * 4];

    // issue all 8 gathers back-to-back (saddr + 32-bit voffset)
    uint2 w00 = *(const uint2*)(base + (c0.x + fb));
    uint2 w01 = *(const uint2*)(base + (c0.y + fb));
    uint2 w02 = *(const uint2*)(base + (c0.z + fb));
    uint2 w03 = *(const uint2*)(base + (c0.w + fb));
    uint2 w10 = *(const uint2*)(base + (c1.x + fb));
    uint2 w11 = *(const uint2*)(base + (c1.y + fb));
    uint2 w12 = *(const uint2*)(base + (c1.z + fb));
    uint2 w13 = *(const uint2*)(base + (c1.w + fb));

    float a[4] = {0, 0, 0, 0}, g[4] = {0, 0, 0, 0};
    float lo, hi;
    unpack_bf16x2(w00.x, lo, hi); a[0] += vf.x * lo; a[1] += vf.x * hi;
    unpack_bf16x2(w00.y, lo, hi); a[2] += vf.x * lo; a[3] += vf.x * hi;
    unpack_bf16x2(w01.x, lo, hi); a[0] += vf.y * lo; a[1] += vf.y * hi;
    unpack_bf16x2(w01.y, lo, hi); a[2] += vf.y * lo; a[3] += vf.y * hi;
    unpack_bf16x2(w02.x, lo, hi); a[0] += vf.z * lo; a[1] += vf.z * hi;
    unpack_bf16x2(w02.y, lo, hi); a[2] += vf.z * lo; a[3] += vf.z * hi;
    unpack_bf16x2(w03.x, lo, hi); a[0] += vf.w * lo; a[1] += vf.w * hi;
    unpack_bf16x2(w03.y, lo, hi); a[2] += vf.w * lo; a[3] += vf.w * hi;
    unpack_bf16x2(w10.x, lo, hi); g[0] += vf.x * lo; g[1] += vf.x * hi;
    unpack_bf16x2(w10.y, lo, hi); g[2] += vf.x * lo; g[3] += vf.x * hi;
    unpack_bf16x2(w11.x, lo, hi); g[0] += vf.y * lo; g[1] += vf.y * hi;
    unpack_bf16x2(w11.y, lo, hi); g[2] += vf.y * lo; g[3] += vf.y * hi;
    unpack_bf16x2(w12.x, lo, hi); g[0] += vf.z * lo; g[1] += vf.z * hi;
    unpack_bf16x2(w12.y, lo, hi); g[2] += vf.z * lo; g[3] += vf.z * hi;
    unpack_bf16x2(w13.x, lo, hi); g[0] += vf.w * lo; g[1] += vf.w * hi;
    unpack_bf16x2(w13.y, lo, hi); g[2] += vf.w * lo; g[3] += vf.w * hi;

    // ---- halving butterfly over k-eighths (lane bits 3,4,5) ----
    // channel ids: a[i] = ch i, g[i] = ch 4+i (feature fp*4+i of side ch>>2)
    bool b3 = (lane & 8)  != 0;
    bool b4 = (lane & 16) != 0;
    bool b5 = (lane & 32) != 0;
    // step 1 (xor 8): keep {a2,a3,g2,g3} if b3 else {a0,a1,g0,g1}
    float k0 = b3 ? a[2] : a[0], o0 = b3 ? a[0] : a[2];
    float k1 = b3 ? a[3] : a[1], o1 = b3 ? a[1] : a[3];
    float k2 = b3 ? g[2] : g[0], o2 = b3 ? g[0] : g[2];
    float k3 = b3 ? g[3] : g[1], o3 = b3 ? g[1] : g[3];
    k0 += __shfl_xor(o0, 8, 64);
    k1 += __shfl_xor(o1, 8, 64);
    k2 += __shfl_xor(o2, 8, 64);
    k3 += __shfl_xor(o3, 8, 64);
    // ch(k0)=2*b3, ch(k1)=1+2*b3, ch(k2)=4+2*b3, ch(k3)=5+2*b3
    // step 2 (xor 16): keep {k1,k3} if b4 else {k0,k2}
    float m0 = b4 ? k1 : k0, s0 = b4 ? k0 : k1;
    float m1 = b4 ? k3 : k2, s1 = b4 ? k2 : k3;
    m0 += __shfl_xor(s0, 16, 64);
    m1 += __shfl_xor(s1, 16, 64);
    // ch(m0)=2*b3+b4, ch(m1)=4+2*b3+b4
    // step 3 (xor 32): keep m1 if b5 else m0
    float rsum = b5 ? m1 : m0, ss = b5 ? m0 : m1;
    rsum += __shfl_xor(ss, 32, 64);
    // lane owns channel c = 4*b5 + 2*b3 + b4: side = b5, feat = fp*4+2*b3+b4

    int side = b5 ? 1 : 0;
    int f    = fp * 4 + (b3 ? 2 : 0) + (b4 ? 1 : 0);
    int fo   = slice * SL_F + f;

    float bsum = b_ft[fo] + b_fft[fo];
    float wo   = W_out[side * FT_OUT + fo];
    float fa   = 0.0f;
    if (row < MODV)
        fa = fft_acc[((size_t)side * MODV + row) * FT_OUT + fo];

    float d = clip01(rsum + bsum + fa) * wo;

    // every (side,feat) channel appears exactly once -> plain wave sum
#pragma unroll
    for (int off = 32; off > 0; off >>= 1)
        d += __shfl_down(d, off, 64);
    if (lane == 0)
        partial[(size_t)slice * B_SZ + row] = d;
}

__global__ __launch_bounds__(256)
void finish(const float* __restrict__ partial, const float* __restrict__ b_out,
            float* __restrict__ out) {
    int row = blockIdx.x * 256 + threadIdx.x;
    float s = b_out[0];
#pragma unroll
    for (int j = 0; j < NSLICE; j++)
        s += partial[(size_t)j * B_SZ + row];
    out[row] = 1.0f / (1.0f + expf(-s));
}

extern "C" void kernel_launch(void* const* d_in, const int* in_sizes, int n_in,
                              void* d_out, int out_size, void* d_ws, size_t ws_size,
                              hipStream_t stream) {
    const int*   stm   = (const int*)d_in[0];
    const int*   nstm  = (const int*)d_in[1];
    const float* vals  = (const float*)d_in[2];
    // d_in[3]: size scalar (compile-time B_SZ)
    const float* W_ft  = (const float*)d_in[4];
    const float* b_ft  = (const float*)d_in[5];
    const float* W_fft = (const float*)d_in[6];
    const float* b_fft = (const float*)d_in[7];
    const float* W_out = (const float*)d_in[8];
    const float* b_out = (const float*)d_in[9];
    float* out = (float*)d_out;

    unsigned short* Wt_bf = (unsigned short*)d_ws;                  // F_BIG*FT_OUT ushort
    float* Wfft_t  = (float*)(Wt_bf + (size_t)F_BIG * FT_OUT);      // MODV*FT_OUT
    float* H       = Wfft_t + (size_t)MODV * FT_OUT;                // 2*MODV*MODV
    float* fft_acc = H + (size_t)2 * MODV * MODV;                   // 2*MODV*FT_OUT
    float* partial = fft_acc + (size_t)2 * MODV * FT_OUT;           // NSLICE*B_SZ

    prep_small<<<PREPS_GRID, 256, 0, stream>>>(W_fft, stm, nstm, vals, Wfft_t, H);
    fft_gemm<<<320, 512, 0, stream>>>(H, Wfft_t, fft_acc);
    prep_big<<<TP_A, 256, 0, stream>>>(W_ft, Wt_bf);
    main_slice<<<MAIN_GRID, 256, 0, stream>>>(stm, nstm, vals, Wt_bf, b_ft, b_fft,
                                              fft_acc, W_out, partial);
    finish<<<B_SZ / 256, 256, 0, stream>>>(partial, b_out, out);
}

// Round 6
// 331.873 us; speedup vs baseline: 1.0116x; 1.0023x over previous
//
#include <hip/hip_runtime.h>
#include <math.h>

#define B_SZ    16384
#define NNZ_PER 32
#define NNZ     (B_SZ * NNZ_PER)
#define FT_OUT  512
#define F_BIG   49152
#define F_SMALL 768
#define MODV    640

// prep_big grid
#define TP_A     1536              // W_ft tiles: 768 c-tiles(64) x 2 o-tiles(256)
// prep_small grid partition
#define TP_B     80                // W_fft 64x64 tiles: 8 ot x 10 ct
#define HISTB    (2 * MODV)        // 1280: one block per (side, histogram row r)
#define PREPS_GRID (TP_B + HISTB)

// main slicing: 16 slices x 32 features, slice-major Wt layout [s][col][32]
#define NSLICE  16
#define SL_F    32
#define ROWS_PER_BLOCK 8                           // 4 waves x 2 rows
#define MAIN_GRID (NSLICE * (B_SZ / ROWS_PER_BLOCK))   // 32768

// fft_gemm v3 geometry: 2 sides x 40 s-tiles(16) x 4 o-quarters(128)
#define FFT_SROWS 16
#define FFT_OQ    128
#define FFT_BLOCKS (2 * (MODV / FFT_SROWS) * (FT_OUT / FFT_OQ))   // 320

// ---------------------------------------------------------------------------
// ws layout:
//   Wt_bf   : F_BIG*FT_OUT ushort      48 MB  slice-major bf16 weight
//   Wfft_t  : MODV*FT_OUT float        1.3 MB transposed small weight (fp32)
//   H       : 2*MODV*MODV float        3.3 MB weighted histograms
//   fft_acc : 2*MODV*FT_OUT float      2.6 MB H @ Wfft^T per side
//   partial : NSLICE*B_SZ float        1.0 MB per-slice partial dots
// ---------------------------------------------------------------------------

__device__ __forceinline__ unsigned short f32_to_bf16_rne(float f) {
    union { float f; unsigned int u; } v; v.f = f;
    unsigned int u = v.u;
    return (unsigned short)((u + 0x7fffu + ((u >> 16) & 1u)) >> 16);
}

__device__ __forceinline__ void unpack_bf16x2(unsigned int u, float& lo, float& hi) {
    union { unsigned int i; float f; } a, b;
    a.i = u << 16;            // even element
    b.i = u & 0xffff0000u;    // odd element
    lo = a.f; hi = b.f;
}

__device__ __forceinline__ float clip01(float x) {
    return fminf(fmaxf(x, 0.0f), 1.0f);
}

// ---- W_ft transpose+quantize into slice-major layout ----------------------
__global__ __launch_bounds__(256)
void prep_big(const float* __restrict__ W_ft, unsigned short* __restrict__ Wt) {
    __shared__ __align__(16) unsigned short tA[256][68];   // 34.8 KB
    int b = blockIdx.x;
    int tid = threadIdx.x;
    int ct = b >> 1, ot = b & 1;
    int c0 = ct * 64, o0 = ot * 256;
    int orow = tid >> 4, c4 = (tid & 15) * 4;
#pragma unroll
    for (int it = 0; it < 16; it++) {
        int oo = orow + it * 16;
        float4 f = *(const float4*)(W_ft + (size_t)(o0 + oo) * F_BIG + c0 + c4);
        tA[oo][c4 + 0] = f32_to_bf16_rne(f.x);
        tA[oo][c4 + 1] = f32_to_bf16_rne(f.y);
        tA[oo][c4 + 2] = f32_to_bf16_rne(f.z);
        tA[oo][c4 + 3] = f32_to_bf16_rne(f.w);
    }
    __syncthreads();
    int cc = tid & 63, och = tid >> 6;      // och 0..3
    int obase = och * 64;
#pragma unroll
    for (int k = 0; k < 8; k++) {
        int o8 = obase + k * 8;
        uint4 pk;
        pk.x = (unsigned int)tA[o8 + 0][cc] | ((unsigned int)tA[o8 + 1][cc] << 16);
        pk.y = (unsigned int)tA[o8 + 2][cc] | ((unsigned int)tA[o8 + 3][cc] << 16);
        pk.z = (unsigned int)tA[o8 + 4][cc] | ((unsigned int)tA[o8 + 5][cc] << 16);
        pk.w = (unsigned int)tA[o8 + 6][cc] | ((unsigned int)tA[o8 + 7][cc] << 16);
        int og = o0 + o8;                    // global o of first elem (mult of 8)
        int s  = og >> 5;                    // slice
        int f  = og & 31;                    // offset within slice (0,8,16,24)
        *(uint4*)(Wt + ((size_t)s * F_BIG + (c0 + cc)) * SL_F + f) = pk;
    }
}

// ---- W_fft transpose + LDS-private histogram ------------------------------
__global__ __launch_bounds__(256)
void prep_small(const float* __restrict__ W_fft,
                const int* __restrict__ stm, const int* __restrict__ nstm,
                const float* __restrict__ vals,
                float* __restrict__ Wfft_t, float* __restrict__ H) {
    __shared__ __align__(16) float smem[64 * 65];          // 16.6 KB
    int b = blockIdx.x;
    int tid = threadIdx.x;
    if (b < TP_B) {
        float (*tB)[65] = (float (*)[65])smem;
        int nct = MODV / 64;
        int ot = b / nct, ct = b % nct;
        int c0 = ct * 64, o0 = ot * 64;
        int rr = tid >> 4, c4 = (tid & 15) * 4;
#pragma unroll
        for (int it = 0; it < 4; it++) {
            int oo = rr + it * 16;
            float4 f = *(const float4*)(W_fft + (size_t)(o0 + oo) * F_SMALL + c0 + c4);
            tB[oo][c4 + 0] = f.x; tB[oo][c4 + 1] = f.y;
            tB[oo][c4 + 2] = f.z; tB[oo][c4 + 3] = f.w;
        }
        __syncthreads();
#pragma unroll
        for (int it = 0; it < 4; it++) {
            int idx = tid + it * 256;
            int cc = idx >> 4, g = idx & 15;
            float4 v = make_float4(tB[g * 4 + 0][cc], tB[g * 4 + 1][cc],
                                   tB[g * 4 + 2][cc], tB[g * 4 + 3][cc]);
            *(float4*)(Wfft_t + (size_t)(c0 + cc) * FT_OUT + o0 + g * 4) = v;
        }
    } else {
        // one block per (side, r): build 640-float histogram row in LDS.
        // COO rows are repeat(arange(B),32) so r = (j/32) % 640 is index-known.
        float* hrow = smem;
        int hb   = b - TP_B;                         // 0..1279
        int side = (hb >= MODV) ? 1 : 0;
        int r    = hb - side * MODV;
        const int* cols = (side ? nstm : stm) + NNZ; // col indices at offset NNZ
        for (int i = tid; i < MODV; i += 256) hrow[i] = 0.0f;
        __syncthreads();
        int nb  = (B_SZ - r + MODV - 1) / MODV;      // batch rows with row%640==r
        int tot = nb * NNZ_PER;
        for (int idx = tid; idx < tot; idx += 256) {
            int j = r * NNZ_PER + (idx >> 5) * (MODV * NNZ_PER) + (idx & 31);
            int c = cols[j] % MODV;
            atomicAdd(&hrow[c], vals[j]);
        }
        __syncthreads();
        float* dst = H + ((size_t)side * MODV + r) * MODV;
        for (int i = tid; i < MODV; i += 256) dst[i] = hrow[i];
    }
}

// acc[side][s][o] = sum_cc H[side][s][cc] * Wfft_t[cc][o]
// v3: 320 blocks x 256 thr = 2 sides x 40 s-tiles(16 rows) x 4 o-quarters.
// Wfft_t re-read: 320 x 0.33 MB = 104 MB (was 416 MB). 8 accs/thread,
// H rows LDS-broadcast, 8-deep W prefetch. All 256 CUs busy.
__global__ __launch_bounds__(256)
void fft_gemm(const float* __restrict__ H, const float* __restrict__ Wfft_t,
              float* __restrict__ acc) {
    __shared__ float hst[FFT_SROWS][MODV];           // 40 KB
    int b = blockIdx.x;
    int tid = threadIdx.x;
    int side  = b / 160;
    int rem   = b % 160;
    int s0    = (rem >> 2) * FFT_SROWS;
    int oq    = rem & 3;
    int o     = oq * FFT_OQ + (tid & 127);
    int jh    = (tid >> 7) * 8;                      // row-half: 0 or 8

    const float* Hs = H + ((size_t)side * MODV + s0) * MODV;
    for (int t = tid; t < FFT_SROWS * MODV; t += 256)
        ((float*)hst)[t] = Hs[t];
    __syncthreads();

    float a[8] = {0, 0, 0, 0, 0, 0, 0, 0};
    const float* wp = Wfft_t + o;
    for (int cc0 = 0; cc0 < MODV; cc0 += 8) {
        float w[8];
#pragma unroll
        for (int u = 0; u < 8; u++) w[u] = wp[(size_t)(cc0 + u) * FT_OUT];
#pragma unroll
        for (int u = 0; u < 8; u++) {
#pragma unroll
            for (int j = 0; j < 8; j++)
                a[j] += hst[jh + j][cc0 + u] * w[u];
        }
    }
    float* dst = acc + ((size_t)side * MODV + s0 + jh) * FT_OUT + o;
#pragma unroll
    for (int j = 0; j < 8; j++) dst[(size_t)j * FT_OUT] = a[j];
}

// XCD-sliced gather main, R6: real MLP.
// R5 lesson: VGPR=24 (compiler max-occupancy heuristic) -> the "8 loads in
// flight" were serialized (8 x ~250cy exposed L2 latency per row). Fix:
// __launch_bounds__(256,4) lifts the VGPR cap to ~128, and each wave now
// owns 2 rows -> 16 uint2 gathers declared up-front and co-resident, two
// independent unpack chains (ILP), shared bias/W_out epilogue.
// Lane mapping (per row): q = lane>>3 (k-eighth), fp = lane&7 (feature quad).
// Halving butterfly (verified R5): lane ends owning channel side=b5,
// f = fp*4 + 2*b3 + b4.
__global__ __launch_bounds__(256, 4)
void main_slice(const int* __restrict__ stm, const int* __restrict__ nstm,
                const float* __restrict__ vals,
                const unsigned short* __restrict__ Wt,
                const float* __restrict__ b_ft, const float* __restrict__ b_fft,
                const float* __restrict__ fft_acc,
                const float* __restrict__ W_out, float* __restrict__ partial) {
    int bid   = blockIdx.x;
    int phase = bid >> 14;                       // 16384 blocks per phase
    int slice = (bid & 7) + (phase << 3);
    int rowgrp = (bid & 16383) >> 3;
    int row0 = rowgrp * ROWS_PER_BLOCK;
    int tid = threadIdx.x;

    __shared__ __align__(16) unsigned s_ct[ROWS_PER_BLOCK][2][32]; // col<<6
    __shared__ __align__(16) float    s_vf[ROWS_PER_BLOCK][32];

    {
        // cols: 8 rows x 2 sides x 32 k = 512 entries
        for (int e = tid; e < 512; e += 256) {
            int r = e >> 6, side = (e >> 5) & 1, k = e & 31;
            int tk = (k & 7) * 4 + (k >> 3);     // transpose: [q][kb]
            const int* arr = side ? nstm : stm;
            s_ct[r][side][tk] = (unsigned)arr[NNZ + (row0 + r) * NNZ_PER + k] << 6;
        }
        // vals: 8 rows x 32 k = 256 entries
        int r = tid >> 5, k = tid & 31;
        s_vf[r][(k & 7) * 4 + (k >> 3)] = vals[(row0 + r) * NNZ_PER + k];
    }
    __syncthreads();

    int wid  = tid >> 6;
    int lane = tid & 63;
    int rA   = row0 + wid * 2;                   // this wave's two rows
    int q    = lane >> 3;
    int fp   = lane & 7;

    const char* base = (const char*)Wt + (size_t)slice * ((size_t)F_BIG * 64);
    unsigned fb = (unsigned)fp * 8u;

    uint4  cA0 = *(const uint4*)&s_ct[wid * 2][0][q * 4];
    uint4  cA1 = *(const uint4*)&s_ct[wid * 2][1][q * 4];
    float4 vA  = *(const float4*)&s_vf[wid * 2][q * 4];
    uint4  cB0 = *(const uint4*)&s_ct[wid * 2 + 1][0][q * 4];
    uint4  cB1 = *(const uint4*)&s_ct[wid * 2 + 1][1][q * 4];
    float4 vB  = *(const float4*)&s_vf[wid * 2 + 1][q * 4];

    // 16 gathers, all issued before any use (needs the VGPR headroom)
    uint2 wA00 = *(const uint2*)(base + (cA0.x + fb));
    uint2 wA01 = *(const uint2*)(base + (cA0.y + fb));
    uint2 wA02 = *(const uint2*)(base + (cA0.z + fb));
    uint2 wA03 = *(const uint2*)(base + (cA0.w + fb));
    uint2 wA10 = *(const uint2*)(base + (cA1.x + fb));
    uint2 wA11 = *(const uint2*)(base + (cA1.y + fb));
    uint2 wA12 = *(const uint2*)(base + (cA1.z + fb));
    uint2 wA13 = *(const uint2*)(base + (cA1.w + fb));
    uint2 wB00 = *(const uint2*)(base + (cB0.x + fb));
    uint2 wB01 = *(const uint2*)(base + (cB0.y + fb));
    uint2 wB02 = *(const uint2*)(base + (cB0.z + fb));
    uint2 wB03 = *(const uint2*)(base + (cB0.w + fb));
    uint2 wB10 = *(const uint2*)(base + (cB1.x + fb));
    uint2 wB11 = *(const uint2*)(base + (cB1.y + fb));
    uint2 wB12 = *(const uint2*)(base + (cB1.z + fb));
    uint2 wB13 = *(const uint2*)(base + (cB1.w + fb));

    float aA[4] = {0, 0, 0, 0}, gA[4] = {0, 0, 0, 0};
    float aB[4] = {0, 0, 0, 0}, gB[4] = {0, 0, 0, 0};
    float lo, hi;
    unpack_bf16x2(wA00.x, lo, hi); aA[0] += vA.x * lo; aA[1] += vA.x * hi;
    unpack_bf16x2(wA00.y, lo, hi); aA[2] += vA.x * lo; aA[3] += vA.x * hi;
    unpack_bf16x2(wA01.x, lo, hi); aA[0] += vA.y * lo; aA[1] += vA.y * hi;
    unpack_bf16x2(wA01.y, lo, hi); aA[2] += vA.y * lo; aA[3] += vA.y * hi;
    unpack_bf16x2(wA02.x, lo, hi); aA[0] += vA.z * lo; aA[1] += vA.z * hi;
    unpack_bf16x2(wA02.y, lo, hi); aA[2] += vA.z * lo; aA[3] += vA.z * hi;
    unpack_bf16x2(wA03.x, lo, hi); aA[0] += vA.w * lo; aA[1] += vA.w * hi;
    unpack_bf16x2(wA03.y, lo, hi); aA[2] += vA.w * lo; aA[3] += vA.w * hi;
    unpack_bf16x2(wA10.x, lo, hi); gA[0] += vA.x * lo; gA[1] += vA.x * hi;
    unpack_bf16x2(wA10.y, lo, hi); gA[2] += vA.x * lo; gA[3] += vA.x * hi;
    unpack_bf16x2(wA11.x, lo, hi); gA[0] += vA.y * lo; gA[1] += vA.y * hi;
    unpack_bf16x2(wA11.y, lo, hi); gA[2] += vA.y * lo; gA[3] += vA.y * hi;
    unpack_bf16x2(wA12.x, lo, hi); gA[0] += vA.z * lo; gA[1] += vA.z * hi;
    unpack_bf16x2(wA12.y, lo, hi); gA[2] += vA.z * lo; gA[3] += vA.z * hi;
    unpack_bf16x2(wA13.x, lo, hi); gA[0] += vA.w * lo; gA[1] += vA.w * hi;
    unpack_bf16x2(wA13.y, lo, hi); gA[2] += vA.w * lo; gA[3] += vA.w * hi;
    unpack_bf16x2(wB00.x, lo, hi); aB[0] += vB.x * lo; aB[1] += vB.x * hi;
    unpack_bf16x2(wB00.y, lo, hi); aB[2] += vB.x * lo; aB[3] += vB.x * hi;
    unpack_bf16x2(wB01.x, lo, hi); aB[0] += vB.y * lo; aB[1] += vB.y * hi;
    unpack_bf16x2(wB01.y, lo, hi); aB[2] += vB.y * lo; aB[3] += vB.y * hi;
    unpack_bf16x2(wB02.x, lo, hi); aB[0] += vB.z * lo; aB[1] += vB.z * hi;
    unpack_bf16x2(wB02.y, lo, hi); aB[2] += vB.z * lo; aB[3] += vB.z * hi;
    unpack_bf16x2(wB03.x, lo, hi); aB[0] += vB.w * lo; aB[1] += vB.w * hi;
    unpack_bf16x2(wB03.y, lo, hi); aB[2] += vB.w * lo; aB[3] += vB.w * hi;
    unpack_bf16x2(wB10.x, lo, hi); gB[0] += vB.x * lo; gB[1] += vB.x * hi;
    unpack_bf16x2(wB10.y, lo, hi); gB[2] += vB.x * lo; gB[3] += vB.x * hi;
    unpack_bf16x2(wB11.x, lo, hi); gB[0] += vB.y * lo; gB[1] += vB.y * hi;
    unpack_bf16x2(wB11.y, lo, hi); gB[2] += vB.y * lo; gB[3] += vB.y * hi;
    unpack_bf16x2(wB12.x, lo, hi); gB[0] += vB.z * lo; gB[1] += vB.z * hi;
    unpack_bf16x2(wB12.y, lo, hi); gB[2] += vB.z * lo; gB[3] += vB.z * hi;
    unpack_bf16x2(wB13.x, lo, hi); gB[0] += vB.w * lo; gB[1] += vB.w * hi;
    unpack_bf16x2(wB13.y, lo, hi); gB[2] += vB.w * lo; gB[3] += vB.w * hi;

    bool b3 = (lane & 8)  != 0;
    bool b4 = (lane & 16) != 0;
    bool b5 = (lane & 32) != 0;

    // ---- halving butterfly, row A ----
    float k0 = b3 ? aA[2] : aA[0], o0 = b3 ? aA[0] : aA[2];
    float k1 = b3 ? aA[3] : aA[1], o1 = b3 ? aA[1] : aA[3];
    float k2 = b3 ? gA[2] : gA[0], o2 = b3 ? gA[0] : gA[2];
    float k3 = b3 ? gA[3] : gA[1], o3 = b3 ? gA[1] : gA[3];
    k0 += __shfl_xor(o0, 8, 64);
    k1 += __shfl_xor(o1, 8, 64);
    k2 += __shfl_xor(o2, 8, 64);
    k3 += __shfl_xor(o3, 8, 64);
    float m0 = b4 ? k1 : k0, s0 = b4 ? k0 : k1;
    float m1 = b4 ? k3 : k2, s1 = b4 ? k2 : k3;
    m0 += __shfl_xor(s0, 16, 64);
    m1 += __shfl_xor(s1, 16, 64);
    float rsumA = b5 ? m1 : m0, ssA = b5 ? m0 : m1;
    rsumA += __shfl_xor(ssA, 32, 64);

    // ---- halving butterfly, row B ----
    k0 = b3 ? aB[2] : aB[0]; o0 = b3 ? aB[0] : aB[2];
    k1 = b3 ? aB[3] : aB[1]; o1 = b3 ? aB[1] : aB[3];
    k2 = b3 ? gB[2] : gB[0]; o2 = b3 ? gB[0] : gB[2];
    k3 = b3 ? gB[3] : gB[1]; o3 = b3 ? gB[1] : gB[3];
    k0 += __shfl_xor(o0, 8, 64);
    k1 += __shfl_xor(o1, 8, 64);
    k2 += __shfl_xor(o2, 8, 64);
    k3 += __shfl_xor(o3, 8, 64);
    m0 = b4 ? k1 : k0; s0 = b4 ? k0 : k1;
    m1 = b4 ? k3 : k2; s1 = b4 ? k2 : k3;
    m0 += __shfl_xor(s0, 16, 64);
    m1 += __shfl_xor(s1, 16, 64);
    float rsumB = b5 ? m1 : m0, ssB = b5 ? m0 : m1;
    rsumB += __shfl_xor(ssB, 32, 64);

    // lane owns channel: side = b5, feat = fp*4 + 2*b3 + b4 (shared by A,B)
    int side = b5 ? 1 : 0;
    int f    = fp * 4 + (b3 ? 2 : 0) + (b4 ? 1 : 0);
    int fo   = slice * SL_F + f;

    float bsum = b_ft[fo] + b_fft[fo];
    float wo   = W_out[side * FT_OUT + fo];
    float faA = 0.0f, faB = 0.0f;
    if (rA < MODV)
        faA = fft_acc[((size_t)side * MODV + rA) * FT_OUT + fo];
    if (rA + 1 < MODV)
        faB = fft_acc[((size_t)side * MODV + rA + 1) * FT_OUT + fo];

    float dA = clip01(rsumA + bsum + faA) * wo;
    float dB = clip01(rsumB + bsum + faB) * wo;

#pragma unroll
    for (int off = 32; off > 0; off >>= 1) {
        dA += __shfl_down(dA, off, 64);
        dB += __shfl_down(dB, off, 64);
    }
    if (lane == 0)
        *(float2*)&partial[(size_t)slice * B_SZ + rA] = make_float2(dA, dB);
}

__global__ __launch_bounds__(256)
void finish(const float* __restrict__ partial, const float* __restrict__ b_out,
            float* __restrict__ out) {
    int row = blockIdx.x * 256 + threadIdx.x;
    float s = b_out[0];
#pragma unroll
    for (int j = 0; j < NSLICE; j++)
        s += partial[(size_t)j * B_SZ + row];
    out[row] = 1.0f / (1.0f + expf(-s));
}

extern "C" void kernel_launch(void* const* d_in, const int* in_sizes, int n_in,
                              void* d_out, int out_size, void* d_ws, size_t ws_size,
                              hipStream_t stream) {
    const int*   stm   = (const int*)d_in[0];
    const int*   nstm  = (const int*)d_in[1];
    const float* vals  = (const float*)d_in[2];
    // d_in[3]: size scalar (compile-time B_SZ)
    const float* W_ft  = (const float*)d_in[4];
    const float* b_ft  = (const float*)d_in[5];
    const float* W_fft = (const float*)d_in[6];
    const float* b_fft = (const float*)d_in[7];
    const float* W_out = (const float*)d_in[8];
    const float* b_out = (const float*)d_in[9];
    float* out = (float*)d_out;

    unsigned short* Wt_bf = (unsigned short*)d_ws;                  // F_BIG*FT_OUT ushort
    float* Wfft_t  = (float*)(Wt_bf + (size_t)F_BIG * FT_OUT);      // MODV*FT_OUT
    float* H       = Wfft_t + (size_t)MODV * FT_OUT;                // 2*MODV*MODV
    float* fft_acc = H + (size_t)2 * MODV * MODV;                   // 2*MODV*FT_OUT
    float* partial = fft_acc + (size_t)2 * MODV * FT_OUT;           // NSLICE*B_SZ

    prep_small<<<PREPS_GRID, 256, 0, stream>>>(W_fft, stm, nstm, vals, Wfft_t, H);
    fft_gemm<<<FFT_BLOCKS, 256, 0, stream>>>(H, Wfft_t, fft_acc);
    prep_big<<<TP_A, 256, 0, stream>>>(W_ft, Wt_bf);
    main_slice<<<MAIN_GRID, 256, 0, stream>>>(stm, nstm, vals, Wt_bf, b_ft, b_fft,
                                              fft_acc, W_out, partial);
    finish<<<B_SZ / 256, 256, 0, stream>>>(partial, b_out, out);
}